// Round 2
// baseline (31669.769 us; speedup 1.0000x reference)
//
#include <hip/hip_runtime.h>
#include <hip/hip_cooperative_groups.h>
#include <math.h>

namespace cg = cooperative_groups;

#define Tn 128
#define Bn 64
#define En 512
#define Hn 1024
#define Vn 10000
#define G4n 4096

#define AGLD(p)    __hip_atomic_load((p), __ATOMIC_RELAXED, __HIP_MEMORY_SCOPE_AGENT)
#define AGST(p, v) __hip_atomic_store((p), (v), __ATOMIC_RELAXED, __HIP_MEMORY_SCOPE_AGENT)

// ---------------------------------------------------------------------------
// Tiled FP32 GEMM (NT): C[M,N] = A[M,K] @ B[N,K]^T + bias0 + bias1
// BM=BN=128, BK=16, 256 threads, 8x8 micro-tile held as two 4-wide halves.
// ---------------------------------------------------------------------------
__global__ __launch_bounds__(256) void gemm_nt_128(
    const int* __restrict__ gather, const float* __restrict__ A,
    const float* __restrict__ B, const float* __restrict__ bias0,
    const float* __restrict__ bias1, float* __restrict__ C,
    int M, int N, int K)
{
    __shared__ alignas(16) float As[16][132];
    __shared__ alignas(16) float Bs[16][132];
    const int bm = blockIdx.x * 128;
    const int bn = blockIdx.y * 128;
    const int tid = threadIdx.x;
    const int tx = tid & 15;
    const int ty = tid >> 4;

    float acc[8][8];
#pragma unroll
    for (int i = 0; i < 8; ++i)
#pragma unroll
        for (int j = 0; j < 8; ++j) acc[i][j] = 0.f;

    for (int k0 = 0; k0 < K; k0 += 16) {
#pragma unroll
        for (int l = 0; l < 2; ++l) {
            const int slot = tid + l * 256;
            const int row  = slot >> 2;
            const int c4   = (slot & 3) << 2;
            const int ar = bm + row;
            const int sr = gather ? gather[ar] : ar;
            const float4 va = *(const float4*)(A + (size_t)sr * K + k0 + c4);
            As[c4 + 0][row] = va.x; As[c4 + 1][row] = va.y;
            As[c4 + 2][row] = va.z; As[c4 + 3][row] = va.w;
            const int br = bn + row;
            float4 vb = make_float4(0.f, 0.f, 0.f, 0.f);
            if (br < N) vb = *(const float4*)(B + (size_t)br * K + k0 + c4);
            Bs[c4 + 0][row] = vb.x; Bs[c4 + 1][row] = vb.y;
            Bs[c4 + 2][row] = vb.z; Bs[c4 + 3][row] = vb.w;
        }
        __syncthreads();
#pragma unroll
        for (int k = 0; k < 16; ++k) {
            const float4 a0 = *(const float4*)&As[k][ty * 4];
            const float4 a1 = *(const float4*)&As[k][64 + ty * 4];
            const float4 b0 = *(const float4*)&Bs[k][tx * 4];
            const float4 b1 = *(const float4*)&Bs[k][64 + tx * 4];
            const float a[8] = {a0.x, a0.y, a0.z, a0.w, a1.x, a1.y, a1.z, a1.w};
            const float b[8] = {b0.x, b0.y, b0.z, b0.w, b1.x, b1.y, b1.z, b1.w};
#pragma unroll
            for (int i = 0; i < 8; ++i)
#pragma unroll
                for (int j = 0; j < 8; ++j)
                    acc[i][j] = fmaf(a[i], b[j], acc[i][j]);
        }
        __syncthreads();
    }

#pragma unroll
    for (int i = 0; i < 8; ++i) {
        const int r = bm + ((i < 4) ? (ty * 4 + i) : (64 + ty * 4 + i - 4));
#pragma unroll
        for (int j = 0; j < 8; ++j) {
            const int cc = bn + ((j < 4) ? (tx * 4 + j) : (64 + tx * 4 + j - 4));
            if (cc < N) {
                float bv = 0.f;
                if (bias0) bv += bias0[cc];
                if (bias1) bv += bias1[cc];
                C[(size_t)r * N + cc] = acc[i][j] + bv;
            }
        }
    }
}

// ---------------------------------------------------------------------------
// Persistent LSTM recurrence (cooperative). Grid 512 = 64 cgp x 8 kc.
// LDS only 32 KiB/block (Wl 16K + hl 16K) so 2 blocks/CU is legal under ANY
// cooperative-occupancy model (the round-1 64 KiB version was rejected).
// Per step, two 64-k sub-phases: stage W slice (from L2) + h chunk into LDS,
// 4x4-register-tile FMA; write per-kc partial gates to gpart (agent-scope);
// grid.sync; phase B: 1 cell/thread (tid<128), c in register across all 128
// steps; write hs + double-buffered hT (agent-scope); grid.sync.
// ---------------------------------------------------------------------------
__global__ __launch_bounds__(256, 2) void lstm_persistent(
    const float* __restrict__ W_hh,   // [4096][1024]
    const float* __restrict__ h0,     // [64][1024]
    const float* __restrict__ c0,     // [64][1024]
    const float* __restrict__ xi,     // [128*64][4096]
    float* __restrict__ hs,           // [128*64][1024]
    float* __restrict__ hT,           // [2][1024][64]
    float* __restrict__ gpart)        // [8][64][4096] scratch (in d_out)
{
    __shared__ float Wl[64 * 64];     // [k][c] 16 KB, re-staged per sub-phase
    __shared__ float hl[64 * 64];     // [k][b] 16 KB

    const int tid = threadIdx.x;
    const int bid = blockIdx.x;
    const int cgp = bid >> 3;          // 0..63 (64 gate-cols)
    const int kc  = bid & 7;           // 0..7  (128-k chunk)
    const int c0r = cgp * 64;
    const int k0  = kc * 128;

    // phase-B identity: 1 cell per thread for tid<128
    const int myb = (bid & 7) * 8 + (tid >> 4);
    const int myh = (bid >> 3) * 16 + (tid & 15);

    float creg = 0.f;
    if (tid < 128) {
        creg = c0[(size_t)myb * Hn + myh];
        AGST(&hT[(size_t)myh * Bn + myb], h0[(size_t)myb * Hn + myh]);
    }

    const int c4 = tid >> 4;   // 0..15 col group (4 cols)
    const int b4 = tid & 15;   // 0..15 b group (4 b)

    cg::grid_group grid = cg::this_grid();
    __threadfence();
    grid.sync();

    for (int t = 0; t < Tn; ++t) {
        const float* hTt = hT + (size_t)(t & 1) * Hn * Bn;

        float acc[4][4];
#pragma unroll
        for (int i = 0; i < 4; ++i)
#pragma unroll
            for (int j = 0; j < 4; ++j) acc[i][j] = 0.f;

        for (int p = 0; p < 2; ++p) {
            const int kk = k0 + p * 64;
            __syncthreads();                     // protect LDS from prev use
            // stage W slice [64 c][64 k] as Wl[k][c] (conflict-free writes)
#pragma unroll
            for (int i = 0; i < 4; ++i) {
                const int slot = i * 256 + tid;  // 1024 slots = 64 c x 16 q
                const int c = slot & 63;
                const int q = slot >> 6;         // 0..15
                const float4 w =
                    *(const float4*)&W_hh[(size_t)(c0r + c) * Hn + kk + q * 4];
                Wl[(q * 4 + 0) * 64 + c] = w.x;
                Wl[(q * 4 + 1) * 64 + c] = w.y;
                Wl[(q * 4 + 2) * 64 + c] = w.z;
                Wl[(q * 4 + 3) * 64 + c] = w.w;
            }
            // stage h chunk [64 k][64 b], contiguous; agent-scope loads
#pragma unroll
            for (int i = 0; i < 4; ++i) {
                const int idx = (i * 256 + tid) * 4;
                const float* src = &hTt[(size_t)kk * Bn + idx];
                hl[idx + 0] = AGLD(src + 0);
                hl[idx + 1] = AGLD(src + 1);
                hl[idx + 2] = AGLD(src + 2);
                hl[idx + 3] = AGLD(src + 3);
            }
            __syncthreads();
#pragma unroll 4
            for (int k = 0; k < 64; ++k) {
                const float4 w = *(const float4*)&Wl[k * 64 + c4 * 4];  // bcast
                const float4 h = *(const float4*)&hl[k * 64 + b4 * 4];  // 2-way
                const float wv[4] = {w.x, w.y, w.z, w.w};
                const float hv[4] = {h.x, h.y, h.z, h.w};
#pragma unroll
                for (int i = 0; i < 4; ++i)
#pragma unroll
                    for (int j = 0; j < 4; ++j)
                        acc[i][j] = fmaf(hv[j], wv[i], acc[i][j]);  // acc[c][b]
            }
        }

        // write partial gates: gpart[kc][b][c], agent-scope
        float* gp = gpart + (size_t)kc * Bn * G4n;
#pragma unroll
        for (int jb = 0; jb < 4; ++jb) {
            const int b = b4 * 4 + jb;
            float* dst = &gp[(size_t)b * G4n + c0r + c4 * 4];
            AGST(dst + 0, acc[0][jb]);
            AGST(dst + 1, acc[1][jb]);
            AGST(dst + 2, acc[2][jb]);
            AGST(dst + 3, acc[3][jb]);
        }
        __threadfence();
        grid.sync();

        // ---- phase B: one cell per thread (tid<128), c in register ----
        if (tid < 128) {
            const size_t xrow = ((size_t)t * Bn + myb) * G4n + myh;
            float g[4];
#pragma unroll
            for (int gi = 0; gi < 4; ++gi) {
                float s = xi[xrow + (size_t)gi * Hn];
#pragma unroll
                for (int kcc = 0; kcc < 8; ++kcc)
                    s += AGLD(&gpart[((size_t)kcc * Bn + myb) * G4n +
                                     (size_t)gi * Hn + myh]);
                g[gi] = s;
            }
            const float is = 1.f / (1.f + __expf(-g[0]));
            const float fs = 1.f / (1.f + __expf(-g[1]));
            const float e2 = __expf(2.f * g[2]);
            const float gt = 1.f - 2.f / (e2 + 1.f);
            const float os = 1.f / (1.f + __expf(-g[3]));
            const float cn = fs * creg + is * gt;
            creg = cn;
            const float e2c = __expf(2.f * cn);
            const float hn = os * (1.f - 2.f / (e2c + 1.f));
            hs[((size_t)t * Bn + myb) * Hn + myh] = hn;
            AGST(&hT[(size_t)((t + 1) & 1) * Hn * Bn + (size_t)myh * Bn + myb],
                 hn);
        }
        __threadfence();
        grid.sync();
    }
}

// ---------------------------------------------------------------------------
// FALLBACK path (verified round-0 kernels) — used if cooperative launch is
// rejected by the runtime for any reason.
// ---------------------------------------------------------------------------
__global__ __launch_bounds__(256) void transpose32(
    const float* __restrict__ in, float* __restrict__ out, int R, int C)
{
    __shared__ float tile[32][33];
    const int c0 = blockIdx.x * 32, r0 = blockIdx.y * 32;
    const int j = threadIdx.x & 31, i0 = threadIdx.x >> 5;
#pragma unroll
    for (int ii = 0; ii < 4; ++ii) {
        const int i = i0 * 4 + ii;
        tile[i][j] = in[(size_t)(r0 + i) * C + c0 + j];
    }
    __syncthreads();
#pragma unroll
    for (int ii = 0; ii < 4; ++ii) {
        const int i = i0 * 4 + ii;
        out[(size_t)(c0 + i) * R + r0 + j] = tile[j][i];
    }
}

__global__ __launch_bounds__(256, 2) void lstm_step_fused(
    const float* __restrict__ W_hh, float* __restrict__ hT,
    float* __restrict__ cbuf, float* __restrict__ xi,
    float* __restrict__ hs, int* __restrict__ cnt, int t)
{
    __shared__ alignas(16) float smem[8448];
    float* Wl = smem;          // [64 c][68 k-padded]
    float* hl = smem + 4352;   // [64 k][64 b]

    const int tid  = threadIdx.x;
    const int bid  = blockIdx.x;
    const int hg   = bid & 15;
    const int gate = (bid >> 4) & 3;
    const int kc   = bid >> 6;
    const int c0   = gate * Hn + hg * 64;
    const int k0   = kc * 128;
    const float* hTt = hT + (size_t)(t & 1) * Hn * Bn;

    const int bg = tid & 15;
    const int cg = tid >> 4;

    float acc[4][4];
#pragma unroll
    for (int i = 0; i < 4; ++i)
#pragma unroll
        for (int j = 0; j < 4; ++j) acc[i][j] = 0.f;

    for (int sub = 0; sub < 2; ++sub) {
        const int kk = k0 + sub * 64;
        __syncthreads();
#pragma unroll
        for (int j = 0; j < 4; ++j) {
            const int slot = j * 256 + tid;
            const int row  = slot >> 4;
            const int q4   = (slot & 15) << 2;
            *(float4*)&Wl[row * 68 + q4] =
                *(const float4*)&W_hh[(size_t)(c0 + row) * Hn + kk + q4];
            *(float4*)&hl[row * 64 + q4] =
                *(const float4*)&hTt[(size_t)(kk + row) * Bn + q4];
        }
        __syncthreads();
#pragma unroll 4
        for (int k = 0; k < 64; k += 4) {
            float wr[4][4], hr[4][4];
#pragma unroll
            for (int j = 0; j < 4; ++j)
                *(float4*)wr[j] = *(const float4*)&Wl[(cg * 4 + j) * 68 + k];
#pragma unroll
            for (int dk = 0; dk < 4; ++dk)
                *(float4*)hr[dk] = *(const float4*)&hl[(k + dk) * 64 + bg * 4];
#pragma unroll
            for (int dk = 0; dk < 4; ++dk)
#pragma unroll
                for (int i = 0; i < 4; ++i)
#pragma unroll
                    for (int j = 0; j < 4; ++j)
                        acc[i][j] = fmaf(hr[dk][i], wr[j][dk], acc[i][j]);
        }
    }

    float* xit = xi + (size_t)t * Bn * G4n;
#pragma unroll
    for (int i = 0; i < 4; ++i) {
        const int b = bg * 4 + i;
#pragma unroll
        for (int j = 0; j < 4; ++j)
            atomicAdd(&xit[(size_t)b * G4n + c0 + cg * 4 + j], acc[i][j]);
    }
    __threadfence();

    __shared__ int lastFlag;
    if (tid == 0)
        lastFlag = (atomicAdd(&cnt[t * 16 + hg], 1) == 31) ? 1 : 0;
    __syncthreads();
    if (!lastFlag) return;
    __threadfence();

    float* bounce = smem;
    float* hTn = hT + (size_t)((t + 1) & 1) * Hn * Bn;
    const int hcl = tid & 63;
    const int h   = hg * 64 + hcl;
#pragma unroll
    for (int i = 0; i < 16; ++i) {
        const int bb = i * 4 + (tid >> 6);
        const float* g = &xit[(size_t)bb * G4n + hg * 64 + hcl];
        const float gi = AGLD(g + 0 * Hn);
        const float gf = AGLD(g + 1 * Hn);
        const float gg = AGLD(g + 2 * Hn);
        const float go = AGLD(g + 3 * Hn);
        const float is = 1.f / (1.f + __expf(-gi));
        const float fs = 1.f / (1.f + __expf(-gf));
        const float e2 = __expf(2.f * gg);
        const float gt = 1.f - 2.f / (e2 + 1.f);
        const float os = 1.f / (1.f + __expf(-go));
        const float cold = cbuf[(size_t)bb * Hn + h];
        const float cn = fs * cold + is * gt;
        const float e2c = __expf(2.f * cn);
        const float hn = os * (1.f - 2.f / (e2c + 1.f));
        cbuf[(size_t)bb * Hn + h] = cn;
        hs[((size_t)t * Bn + bb) * Hn + h] = hn;
        bounce[hcl * 65 + bb] = hn;
    }
    __syncthreads();
#pragma unroll
    for (int i = 0; i < 16; ++i) {
        const int idx = i * 256 + tid;
        const int bb2 = idx & 63;
        const int hr  = idx >> 6;
        hTn[(size_t)(hg * 64 + hr) * Bn + bb2] = bounce[hr * 65 + bb2];
    }
}

// ---------------------------------------------------------------------------
// argmax over V per row (first occurrence on ties). row = t*B + b.
// ---------------------------------------------------------------------------
__global__ __launch_bounds__(256) void argmax_rows(
    const float* __restrict__ logits, float* __restrict__ y)
{
    const int row = blockIdx.x;
    const float* p = logits + (size_t)row * Vn;
    const int tid = threadIdx.x;
    float best = -INFINITY;
    int bi = Vn;
    for (int v = tid; v < Vn; v += 256) {
        const float x = p[v];
        if (x > best) { best = x; bi = v; }
    }
    __shared__ float sv[256];
    __shared__ int   si[256];
    sv[tid] = best; si[tid] = bi;
    __syncthreads();
    for (int s = 128; s > 0; s >>= 1) {
        if (tid < s) {
            const float ov = sv[tid + s];
            const int   oi = si[tid + s];
            if (ov > sv[tid] || (ov == sv[tid] && oi < si[tid])) {
                sv[tid] = ov; si[tid] = oi;
            }
        }
        __syncthreads();
    }
    if (tid == 0) {
        const int t = row >> 6;
        const int b = row & 63;
        y[(size_t)b * Tn + t] = (float)si[0];
    }
}

// ---------------------------------------------------------------------------
extern "C" void kernel_launch(void* const* d_in, const int* in_sizes, int n_in,
                              void* d_out, int out_size, void* d_ws, size_t ws_size,
                              hipStream_t stream)
{
    const int*   x      = (const int*)  d_in[0];
    const float* emb    = (const float*)d_in[2];
    const float* W_ih   = (const float*)d_in[3];
    const float* W_hh   = (const float*)d_in[4];
    const float* b_ih   = (const float*)d_in[5];
    const float* b_hh   = (const float*)d_in[6];
    const float* W_proj = (const float*)d_in[7];
    const float* b_proj = (const float*)d_in[8];
    const float* h0     = (const float*)d_in[9];
    const float* c0     = (const float*)d_in[10];

    float* out    = (float*)d_out;
    float* logits = out;                          // (T,B,V)
    float* ypred  = out + (size_t)Tn * Bn * Vn;   // (B,T)

    float* ws  = (float*)d_ws;
    float* xi  = ws;                              // (T*B, 4H)  134.2 MB
    float* hs  = xi  + (size_t)Tn * Bn * G4n;     // (T*B, H)    33.6 MB
    float* hT  = hs  + (size_t)Tn * Bn * Hn;      // [2][H][B]    0.5 MB
    float* cb  = hT  + (size_t)2 * Hn * Bn;       // [B][H] (fallback only)
    int*   cnt = (int*)(cb + (size_t)Bn * Hn);    // [128][16] (fallback only)
    // gpart scratch lives in the (dead-until-final-GEMM) logits region: 8 MB
    float* gpart = out;

    // xi = emb[x] @ W_ih^T + (b_ih + b_hh)
    {
        dim3 g(Tn * Bn / 128, G4n / 128);
        gemm_nt_128<<<g, 256, 0, stream>>>(x, emb, W_ih, b_ih, b_hh, xi,
                                           Tn * Bn, G4n, En);
    }

    // recurrence: persistent cooperative kernel; fall back to per-step path
    // if the runtime rejects the cooperative launch.
    {
        void* kargs[] = {(void*)&W_hh, (void*)&h0, (void*)&c0, (void*)&xi,
                         (void*)&hs, (void*)&hT, (void*)&gpart};
        hipError_t ce = hipLaunchCooperativeKernel(
            reinterpret_cast<void*>(lstm_persistent), dim3(512), dim3(256),
            kargs, 0, stream);
        if (ce != hipSuccess) {
            hipMemcpyAsync(cb, c0, sizeof(float) * Bn * Hn,
                           hipMemcpyDeviceToDevice, stream);
            hipMemsetAsync(cnt, 0, Tn * 16 * sizeof(int), stream);
            dim3 tg(Hn / 32, Bn / 32);
            transpose32<<<tg, 256, 0, stream>>>(h0, hT, Bn, Hn);
            for (int t = 0; t < Tn; ++t)
                lstm_step_fused<<<512, 256, 0, stream>>>(W_hh, hT, cb, xi, hs,
                                                         cnt, t);
        }
    }

    // logits = hs @ W_proj^T + b_proj
    {
        dim3 g(Tn * Bn / 128, (Vn + 127) / 128);
        gemm_nt_128<<<g, 256, 0, stream>>>(nullptr, hs, W_proj, b_proj, nullptr,
                                           logits, Tn * Bn, Vn, Hn);
    }

    argmax_rows<<<Tn * Bn, 256, 0, stream>>>(logits, ypred);
}

// Round 3
// 6283.315 us; speedup vs baseline: 5.0403x; 5.0403x over previous
//
#include <hip/hip_runtime.h>
#include <math.h>

#define Tn 128
#define Bn 64
#define En 512
#define Hn 1024
#define Vn 10000
#define G4n 4096

// ---------------------------------------------------------------------------
// Tiled FP32 GEMM (NT): C[M,N] = A[M,K] @ B[N,K]^T + bias0 + bias1
// BM=BN=128, BK=16, 256 threads, 8x8 micro-tile held as two 4-wide halves.
// ---------------------------------------------------------------------------
__global__ __launch_bounds__(256) void gemm_nt_128(
    const int* __restrict__ gather, const float* __restrict__ A,
    const float* __restrict__ B, const float* __restrict__ bias0,
    const float* __restrict__ bias1, float* __restrict__ C,
    int M, int N, int K)
{
    __shared__ alignas(16) float As[16][132];
    __shared__ alignas(16) float Bs[16][132];
    const int bm = blockIdx.x * 128;
    const int bn = blockIdx.y * 128;
    const int tid = threadIdx.x;
    const int tx = tid & 15;
    const int ty = tid >> 4;

    float acc[8][8];
#pragma unroll
    for (int i = 0; i < 8; ++i)
#pragma unroll
        for (int j = 0; j < 8; ++j) acc[i][j] = 0.f;

    for (int k0 = 0; k0 < K; k0 += 16) {
#pragma unroll
        for (int l = 0; l < 2; ++l) {
            const int slot = tid + l * 256;
            const int row  = slot >> 2;
            const int c4   = (slot & 3) << 2;
            const int ar = bm + row;
            const int sr = gather ? gather[ar] : ar;
            const float4 va = *(const float4*)(A + (size_t)sr * K + k0 + c4);
            As[c4 + 0][row] = va.x; As[c4 + 1][row] = va.y;
            As[c4 + 2][row] = va.z; As[c4 + 3][row] = va.w;
            const int br = bn + row;
            float4 vb = make_float4(0.f, 0.f, 0.f, 0.f);
            if (br < N) vb = *(const float4*)(B + (size_t)br * K + k0 + c4);
            Bs[c4 + 0][row] = vb.x; Bs[c4 + 1][row] = vb.y;
            Bs[c4 + 2][row] = vb.z; Bs[c4 + 3][row] = vb.w;
        }
        __syncthreads();
#pragma unroll
        for (int k = 0; k < 16; ++k) {
            const float4 a0 = *(const float4*)&As[k][ty * 4];
            const float4 a1 = *(const float4*)&As[k][64 + ty * 4];
            const float4 b0 = *(const float4*)&Bs[k][tx * 4];
            const float4 b1 = *(const float4*)&Bs[k][64 + tx * 4];
            const float a[8] = {a0.x, a0.y, a0.z, a0.w, a1.x, a1.y, a1.z, a1.w};
            const float b[8] = {b0.x, b0.y, b0.z, b0.w, b1.x, b1.y, b1.z, b1.w};
#pragma unroll
            for (int i = 0; i < 8; ++i)
#pragma unroll
                for (int j = 0; j < 8; ++j)
                    acc[i][j] = fmaf(a[i], b[j], acc[i][j]);
        }
        __syncthreads();
    }

#pragma unroll
    for (int i = 0; i < 8; ++i) {
        const int r = bm + ((i < 4) ? (ty * 4 + i) : (64 + ty * 4 + i - 4));
#pragma unroll
        for (int j = 0; j < 8; ++j) {
            const int cc = bn + ((j < 4) ? (tx * 4 + j) : (64 + tx * 4 + j - 4));
            if (cc < N) {
                float bv = 0.f;
                if (bias0) bv += bias0[cc];
                if (bias1) bv += bias1[cc];
                C[(size_t)r * N + cc] = acc[i][j] + bv;
            }
        }
    }
}

// ---------------------------------------------------------------------------
// 32x32 tiled transpose: out[C][R] = in[R][C]^T
// ---------------------------------------------------------------------------
__global__ __launch_bounds__(256) void transpose32(
    const float* __restrict__ in, float* __restrict__ out, int R, int C)
{
    __shared__ float tile[32][33];
    const int c0 = blockIdx.x * 32, r0 = blockIdx.y * 32;
    const int j = threadIdx.x & 31, i0 = threadIdx.x >> 5;
#pragma unroll
    for (int ii = 0; ii < 4; ++ii) {
        const int i = i0 * 4 + ii;
        tile[i][j] = in[(size_t)(r0 + i) * C + c0 + j];
    }
    __syncthreads();
#pragma unroll
    for (int ii = 0; ii < 4; ++ii) {
        const int i = i0 * 4 + ii;
        out[(size_t)(c0 + i) * R + r0 + j] = tile[j][i];
    }
}

// ---------------------------------------------------------------------------
// Gates GEMM for one step (round-0 proven inner loop, atomics removed).
// Grid 512 = (hg 16) x (gate 4) x (kc 8). Block computes a 64c x 64b partial
// over its 128-k chunk and writes it to gpart[kc][b][c] with plain coalesced
// float4 stores. No atomics, no fences, no tail.
// hT: k-major hidden state [1024][64] (single buffer; stream order is the
// barrier between steps). No t dependence at all.
// ---------------------------------------------------------------------------
__global__ __launch_bounds__(256, 2) void lstm_gates(
    const float* __restrict__ W_hh,   // [4096][1024]
    const float* __restrict__ hT,     // [1024][64]
    float* __restrict__ gpart)        // [8][64][4096]
{
    __shared__ alignas(16) float smem[8448];   // 33 KB
    float* Wl = smem;          // [64 c][68 k-padded]
    float* hl = smem + 4352;   // [64 k][64 b]

    const int tid  = threadIdx.x;
    const int bid  = blockIdx.x;
    const int hg   = bid & 15;
    const int gate = (bid >> 4) & 3;
    const int kc   = bid >> 6;              // 0..7
    const int c0   = gate * Hn + hg * 64;
    const int k0   = kc * 128;

    const int bg = tid & 15;                // batch group (4 rows)
    const int cg = tid >> 4;                // col group (4 cols)

    float acc[4][4];
#pragma unroll
    for (int i = 0; i < 4; ++i)
#pragma unroll
        for (int j = 0; j < 4; ++j) acc[i][j] = 0.f;

    for (int sub = 0; sub < 2; ++sub) {
        const int kk = k0 + sub * 64;
        __syncthreads();
#pragma unroll
        for (int j = 0; j < 4; ++j) {
            const int slot = j * 256 + tid;      // 1024 slots = 64 rows x 16 f4
            const int row  = slot >> 4;
            const int q4   = (slot & 15) << 2;
            // W: row=c (c-major), coalesced along k
            *(float4*)&Wl[row * 68 + q4] =
                *(const float4*)&W_hh[(size_t)(c0 + row) * Hn + kk + q4];
            // h: row=k (k-major), coalesced along b
            *(float4*)&hl[row * 64 + q4] =
                *(const float4*)&hT[(size_t)(kk + row) * Bn + q4];
        }
        __syncthreads();
#pragma unroll 4
        for (int k = 0; k < 64; k += 4) {
            float wr[4][4], hr[4][4];
#pragma unroll
            for (int j = 0; j < 4; ++j)
                *(float4*)wr[j] = *(const float4*)&Wl[(cg * 4 + j) * 68 + k];
#pragma unroll
            for (int dk = 0; dk < 4; ++dk)
                *(float4*)hr[dk] = *(const float4*)&hl[(k + dk) * 64 + bg * 4];
#pragma unroll
            for (int dk = 0; dk < 4; ++dk)
#pragma unroll
                for (int i = 0; i < 4; ++i)
#pragma unroll
                    for (int j = 0; j < 4; ++j)
                        acc[i][j] = fmaf(hr[dk][i], wr[j][dk], acc[i][j]);
        }
    }

    // plain coalesced stores of the partial: gpart[kc][b][c0 + cg*4 .. +3]
    float* gp = gpart + (size_t)kc * Bn * G4n;
#pragma unroll
    for (int i = 0; i < 4; ++i) {
        const int b = bg * 4 + i;
        float4 v;
        v.x = acc[i][0]; v.y = acc[i][1]; v.z = acc[i][2]; v.w = acc[i][3];
        *(float4*)&gp[(size_t)b * G4n + c0 + cg * 4] = v;
    }
}

// ---------------------------------------------------------------------------
// Cell update for one step: reduce 8 gpart partials + xi[t], apply LSTM cell,
// write hs[t], cbuf, and the transposed hT for the next step.
// Grid 64 x 256: block hg owns h-cols [hg*16, +16) x all 64 b (4 cells/thr).
// ---------------------------------------------------------------------------
__global__ __launch_bounds__(256) void lstm_cell(
    const float* __restrict__ gpart,  // [8][64][4096]
    const float* __restrict__ xi,     // [128*64][4096]
    float* __restrict__ cbuf,         // [64][1024]
    float* __restrict__ hs,           // [128*64][1024]
    float* __restrict__ hT,           // [1024][64]
    int t)
{
    __shared__ float bounce[16][65];
    const int hg = blockIdx.x;            // 0..63
    const int hh = threadIdx.x & 15;
    const int bg = threadIdx.x >> 4;      // 0..15
    const int h  = hg * 16 + hh;

#pragma unroll
    for (int i = 0; i < 4; ++i) {
        const int b = bg * 4 + i;
        float g[4];
#pragma unroll
        for (int gi = 0; gi < 4; ++gi) {
            float s = xi[((size_t)t * Bn + b) * G4n + (size_t)gi * Hn + h];
#pragma unroll
            for (int kc = 0; kc < 8; ++kc)
                s += gpart[((size_t)kc * Bn + b) * G4n + (size_t)gi * Hn + h];
            g[gi] = s;
        }
        const float is = 1.f / (1.f + __expf(-g[0]));
        const float fs = 1.f / (1.f + __expf(-g[1]));
        const float e2 = __expf(2.f * g[2]);
        const float gt = 1.f - 2.f / (e2 + 1.f);
        const float os = 1.f / (1.f + __expf(-g[3]));
        const float cold = cbuf[(size_t)b * Hn + h];
        const float cn = fs * cold + is * gt;
        const float e2c = __expf(2.f * cn);
        const float hn = os * (1.f - 2.f / (e2c + 1.f));
        cbuf[(size_t)b * Hn + h] = cn;
        hs[((size_t)t * Bn + b) * Hn + h] = hn;
        bounce[hh][b] = hn;
    }
    __syncthreads();
    // coalesced transposed write: hT[h][b]
#pragma unroll
    for (int i = 0; i < 4; ++i) {
        const int idx = i * 256 + threadIdx.x;
        const int r = idx >> 6;           // 0..15
        const int c = idx & 63;
        hT[(size_t)(hg * 16 + r) * Bn + c] = bounce[r][c];
    }
}

// ---------------------------------------------------------------------------
// argmax over V per row (first occurrence on ties). row = t*B + b.
// ---------------------------------------------------------------------------
__global__ __launch_bounds__(256) void argmax_rows(
    const float* __restrict__ logits, float* __restrict__ y)
{
    const int row = blockIdx.x;
    const float* p = logits + (size_t)row * Vn;
    const int tid = threadIdx.x;
    float best = -INFINITY;
    int bi = Vn;
    for (int v = tid; v < Vn; v += 256) {
        const float x = p[v];
        if (x > best) { best = x; bi = v; }
    }
    __shared__ float sv[256];
    __shared__ int   si[256];
    sv[tid] = best; si[tid] = bi;
    __syncthreads();
    for (int s = 128; s > 0; s >>= 1) {
        if (tid < s) {
            const float ov = sv[tid + s];
            const int   oi = si[tid + s];
            if (ov > sv[tid] || (ov == sv[tid] && oi < si[tid])) {
                sv[tid] = ov; si[tid] = oi;
            }
        }
        __syncthreads();
    }
    if (tid == 0) {
        const int t = row >> 6;
        const int b = row & 63;
        y[(size_t)b * Tn + t] = (float)si[0];
    }
}

// ---------------------------------------------------------------------------
extern "C" void kernel_launch(void* const* d_in, const int* in_sizes, int n_in,
                              void* d_out, int out_size, void* d_ws, size_t ws_size,
                              hipStream_t stream)
{
    const int*   x      = (const int*)  d_in[0];
    const float* emb    = (const float*)d_in[2];
    const float* W_ih   = (const float*)d_in[3];
    const float* W_hh   = (const float*)d_in[4];
    const float* b_ih   = (const float*)d_in[5];
    const float* b_hh   = (const float*)d_in[6];
    const float* W_proj = (const float*)d_in[7];
    const float* b_proj = (const float*)d_in[8];
    const float* h0     = (const float*)d_in[9];
    const float* c0     = (const float*)d_in[10];

    float* out    = (float*)d_out;
    float* logits = out;                          // (T,B,V)
    float* ypred  = out + (size_t)Tn * Bn * Vn;   // (B,T)

    float* ws  = (float*)d_ws;
    float* xi  = ws;                              // (T*B, 4H)  134.2 MB
    float* hs  = xi  + (size_t)Tn * Bn * G4n;     // (T*B, H)    33.6 MB
    float* hT  = hs  + (size_t)Tn * Bn * Hn;      // [H][B]      0.25 MB
    float* cb  = hT  + (size_t)2 * Hn * Bn;       // [B][H]
    // gpart scratch lives in the (dead-until-final-GEMM) logits region: 8.4 MB
    float* gpart = out;

    hipMemcpyAsync(cb, c0, sizeof(float) * Bn * Hn, hipMemcpyDeviceToDevice,
                   stream);

    // hT = h0^T  (B x H -> H x B)
    {
        dim3 g(Hn / 32, Bn / 32);
        transpose32<<<g, 256, 0, stream>>>(h0, hT, Bn, Hn);
    }

    // xi = emb[x] @ W_ih^T + (b_ih + b_hh)
    {
        dim3 g(Tn * Bn / 128, G4n / 128);
        gemm_nt_128<<<g, 256, 0, stream>>>(x, emb, W_ih, b_ih, b_hh, xi,
                                           Tn * Bn, G4n, En);
    }

    // recurrence: two small kernels per step, kernel boundary = barrier
    for (int t = 0; t < Tn; ++t) {
        lstm_gates<<<512, 256, 0, stream>>>(W_hh, hT, gpart);
        lstm_cell<<<64, 256, 0, stream>>>(gpart, xi, cb, hs, hT, t);
    }

    // logits = hs @ W_proj^T + b_proj
    {
        dim3 g(Tn * Bn / 128, (Vn + 127) / 128);
        gemm_nt_128<<<g, 256, 0, stream>>>(nullptr, hs, W_proj, b_proj, nullptr,
                                           logits, Tn * Bn, Vn, Hn);
    }

    argmax_rows<<<Tn * Bn, 256, 0, stream>>>(logits, ypred);
}